// Round 2
// baseline (329.099 us; speedup 1.0000x reference)
//
#include <hip/hip_runtime.h>
#include <hip/hip_bf16.h>
#include <stdint.h>

#define NB   16
#define CIN  256
#define CRED 64
#define HW   2304
#define NJT  36   // 2304/64 j-tiles
#define NIG  4    // i-dimension split groups
#define NIT  9    // i-tiles per group (36/4)

typedef __bf16 bf16;
typedef __bf16 bf16x8 __attribute__((ext_vector_type(8)));
typedef __bf16 bf16x4 __attribute__((ext_vector_type(4)));
typedef float  f32x4  __attribute__((ext_vector_type(4)));

// ---------------- Kernel 1: fused QKV 1x1 convs ----------------
// x [N][256][2304] f32 -> qT [N][2304][64] bf16, kT [N][2304][64] bf16, v [N][64][2304] bf16
__global__ __launch_bounds__(256) void qkv_kernel(
    const float* __restrict__ x,
    const float* __restrict__ Wq, const float* __restrict__ bq,
    const float* __restrict__ Wk, const float* __restrict__ bk,
    const float* __restrict__ Wv, const float* __restrict__ bv,
    bf16* __restrict__ qT, bf16* __restrict__ kT, bf16* __restrict__ v)
{
    __shared__ __align__(16) bf16 sX[64 * 264];  // xT[pos][cin], stride 264 (pad 8)
    const int jt = blockIdx.x, n = blockIdx.y;
    const int jbase = jt * 64;
    const int tid = threadIdx.x;
    const int lane = tid & 63, w = tid >> 6;
    const int l15 = lane & 15, q4 = lane >> 4;

    // stage xT (transpose + cvt bf16): coalesced float4 reads, scalar LDS writes
    const float* xn = x + ((size_t)n * CIN) * HW + jbase;
    #pragma unroll
    for (int it = 0; it < 16; ++it) {
        int idx = tid + 256 * it;          // 4096 float4s total
        int c = idx >> 4, p4 = idx & 15;
        const float4 vv = *(const float4*)(xn + c * HW + p4 * 4);
        sX[(p4 * 4 + 0) * 264 + c] = (bf16)vv.x;
        sX[(p4 * 4 + 1) * 264 + c] = (bf16)vv.y;
        sX[(p4 * 4 + 2) * 264 + c] = (bf16)vv.z;
        sX[(p4 * 4 + 3) * 264 + c] = (bf16)vv.w;
    }
    __syncthreads();

    const float* Ws[3] = {Wq, Wk, Wv};
    const float* bs[3] = {bq, bk, bv};
    #pragma unroll
    for (int wi = 0; wi < 3; ++wi) {
        // A-frags from global weights (L2-resident), cvt to bf16
        bf16x8 a[8];
        const float* Wp = Ws[wi] + (w * 16 + l15) * CIN + q4 * 8;
        #pragma unroll
        for (int ks = 0; ks < 8; ++ks) {
            float4 f0 = *(const float4*)(Wp + ks * 32);
            float4 f1 = *(const float4*)(Wp + ks * 32 + 4);
            bf16x8 t = {(bf16)f0.x, (bf16)f0.y, (bf16)f0.z, (bf16)f0.w,
                        (bf16)f1.x, (bf16)f1.y, (bf16)f1.z, (bf16)f1.w};
            a[ks] = t;
        }
        f32x4 acc[4] = {};
        #pragma unroll
        for (int nt = 0; nt < 4; ++nt) {
            #pragma unroll
            for (int ks = 0; ks < 8; ++ks) {
                bf16x8 b = *(const bf16x8*)(sX + (nt * 16 + l15) * 264 + ks * 32 + q4 * 8);
                acc[nt] = __builtin_amdgcn_mfma_f32_16x16x32_bf16(a[ks], b, acc[nt], 0, 0, 0);
            }
        }
        const int crb = w * 16 + q4 * 4;   // C/D row = outc
        const float b0 = bs[wi][crb], b1 = bs[wi][crb + 1],
                    b2 = bs[wi][crb + 2], b3 = bs[wi][crb + 3];
        if (wi < 2) {
            bf16* dst = (wi == 0 ? qT : kT) + ((size_t)n * HW) * 64;
            #pragma unroll
            for (int nt = 0; nt < 4; ++nt) {
                int pos = jbase + nt * 16 + l15;
                bf16x4 pk = {(bf16)(acc[nt].x + b0), (bf16)(acc[nt].y + b1),
                             (bf16)(acc[nt].z + b2), (bf16)(acc[nt].w + b3)};
                *(bf16x4*)(dst + pos * 64 + crb) = pk;
            }
        } else {
            bf16* dst = v + ((size_t)n * CRED) * HW;
            #pragma unroll
            for (int nt = 0; nt < 4; ++nt) {
                int pos = jbase + nt * 16 + l15;
                dst[(crb + 0) * HW + pos] = (bf16)(acc[nt].x + b0);
                dst[(crb + 1) * HW + pos] = (bf16)(acc[nt].y + b1);
                dst[(crb + 2) * HW + pos] = (bf16)(acc[nt].z + b2);
                dst[(crb + 3) * HW + pos] = (bf16)(acc[nt].w + b3);
            }
        }
    }
}

// ---------------- Kernel 2: fused KtQ -> exp -> V*P, i-split 4 ways ----------------
// qT/kT [N][2304][64] bf16, v [N][64][2304] bf16
// -> OTp [NIG][N][2304][64] f32 (unnormalized partials), Z[N]
__global__ __launch_bounds__(256) void attn_kernel(
    const bf16* __restrict__ qT, const bf16* __restrict__ kT,
    const bf16* __restrict__ v,
    float* __restrict__ OTp, float* __restrict__ Z)
{
    __shared__ __align__(16) bf16 sQ[64 * 72];
    __shared__ __align__(16) bf16 sK[64 * 72];
    __shared__ __align__(16) bf16 sV[64 * 72];
    __shared__ __align__(16) bf16 sP[64 * 72];
    const int jt = blockIdx.x, ig = blockIdx.y, n = blockIdx.z;
    const int jbase = jt * 64;
    const int tid = threadIdx.x;
    const int lane = tid & 63, w = tid >> 6;
    const int l15 = lane & 15, q4 = lane >> 4;

    // stage Q tile once: straight copy (qT rows are contiguous 64 bf16 = 8 uint4)
    {
        const uint4* src = (const uint4*)(qT + ((size_t)n * HW + jbase) * 64);
        uint4* dst = (uint4*)sQ;
        for (int i = tid; i < 512; i += 256) {
            int r = i >> 3, c = i & 7;
            dst[r * 9 + c] = src[r * 8 + c];
        }
    }
    __syncthreads();
    // Q fragments are loop-invariant: preload to registers (8 x bf16x8 = 32 VGPRs)
    bf16x8 qf[4][2];
    #pragma unroll
    for (int nt = 0; nt < 4; ++nt)
        #pragma unroll
        for (int ks = 0; ks < 2; ++ks)
            qf[nt][ks] = *(const bf16x8*)(sQ + (nt * 16 + l15) * 72 + ks * 32 + q4 * 8);

    f32x4 oacc[4] = {};
    float zacc = 0.f;
    const uint4* ksrc = (const uint4*)(kT + ((size_t)n * HW) * 64);
    const bf16* vbase = v + ((size_t)n * CRED) * HW;

    for (int it = 0; it < NIT; ++it) {
        const int ibase = (ig * NIT + it) * 64;
        __syncthreads();   // prior iter's reads of sK/sV/sP done
        {   // stage K tile (straight copy) and V tile (row segments)
            uint4* dk = (uint4*)sK;
            uint4* dv = (uint4*)sV;
            const uint4* sk = ksrc + ibase * 8;
            for (int i = tid; i < 512; i += 256) {
                int r = i >> 3, c = i & 7;
                dk[r * 9 + c] = sk[r * 8 + c];
                dv[r * 9 + c] = *(const uint4*)(vbase + r * HW + ibase + c * 8);
            }
        }
        __syncthreads();
        // S = K_i^T Q_j : wave w owns i-rows [16w,16w+16), all 64 j
        bf16x8 kf0 = *(const bf16x8*)(sK + (w * 16 + l15) * 72 + 0 * 32 + q4 * 8);
        bf16x8 kf1 = *(const bf16x8*)(sK + (w * 16 + l15) * 72 + 1 * 32 + q4 * 8);
        #pragma unroll
        for (int nt = 0; nt < 4; ++nt) {
            f32x4 accs = {};
            accs = __builtin_amdgcn_mfma_f32_16x16x32_bf16(kf0, qf[nt][0], accs, 0, 0, 0);
            accs = __builtin_amdgcn_mfma_f32_16x16x32_bf16(kf1, qf[nt][1], accs, 0, 0, 0);
            // exp in fp32 (no max-shift: logits bounded, exp < 1.3e9 fits fp32)
            float p0 = __expf(accs.x), p1 = __expf(accs.y);
            float p2 = __expf(accs.z), p3 = __expf(accs.w);
            zacc += (p0 + p1) + (p2 + p3);
            // P transposed into B-operand layout sP[j][i]
            bf16x4 pk = {(bf16)p0, (bf16)p1, (bf16)p2, (bf16)p3};
            *(bf16x4*)(sP + (nt * 16 + l15) * 72 + w * 16 + q4 * 4) = pk;
        }
        __syncthreads();
        // O += V_i * P : wave w owns c-rows [16w,16w+16)
        bf16x8 vf0 = *(const bf16x8*)(sV + (w * 16 + l15) * 72 + 0 * 32 + q4 * 8);
        bf16x8 vf1 = *(const bf16x8*)(sV + (w * 16 + l15) * 72 + 1 * 32 + q4 * 8);
        #pragma unroll
        for (int nt = 0; nt < 4; ++nt) {
            bf16x8 p0 = *(const bf16x8*)(sP + (nt * 16 + l15) * 72 + 0 * 32 + q4 * 8);
            bf16x8 p1 = *(const bf16x8*)(sP + (nt * 16 + l15) * 72 + 1 * 32 + q4 * 8);
            oacc[nt] = __builtin_amdgcn_mfma_f32_16x16x32_bf16(vf0, p0, oacc[nt], 0, 0, 0);
            oacc[nt] = __builtin_amdgcn_mfma_f32_16x16x32_bf16(vf1, p1, oacc[nt], 0, 0, 0);
        }
    }
    // write unnormalized partial O transposed: OTp[ig][n][pos][cr]
    float* OTn = OTp + (((size_t)ig * NB + n) * HW) * 64;
    #pragma unroll
    for (int nt = 0; nt < 4; ++nt) {
        int pos = jbase + nt * 16 + l15;
        *(f32x4*)(OTn + pos * 64 + w * 16 + q4 * 4) = oacc[nt];
    }
    // per-batch Z: wave reduce then one atomic per wave
    #pragma unroll
    for (int off = 32; off > 0; off >>= 1) zacc += __shfl_down(zacc, off);
    if (lane == 0) atomicAdd(Z + n, zacc);
}

// ---------------- Kernel 3: out = g * (Watt @ (sum_partials(O)/Z) + batt) + g ----------
// 16-pos j-tiles for parallelism: grid (144, 16)
__global__ __launch_bounds__(256) void out_kernel(
    const float* __restrict__ OTp, const float* __restrict__ Z,
    const float* __restrict__ Watt, const float* __restrict__ batt,
    const float* __restrict__ g, float* __restrict__ out)
{
    __shared__ __align__(16) bf16 sO[16 * 72];  // normalized O, [pos][cr]
    const int jt = blockIdx.x, n = blockIdx.y;
    const int jbase = jt * 16;
    const int tid = threadIdx.x;
    const int lane = tid & 63, w = tid >> 6;
    const int l15 = lane & 15, q4 = lane >> 4;
    const float invZ = 1.0f / Z[n];

    // sum 4 partials, normalize, cvt bf16: 256 threads x 1 float4 each
    {
        int r = tid >> 4, c4 = tid & 15;
        const float* p = OTp + (((size_t)n * HW) + jbase + r) * 64 + c4 * 4;
        float4 v0 = *(const float4*)(p);
        float4 v1 = *(const float4*)(p + (size_t)NB * HW * 64);
        float4 v2 = *(const float4*)(p + 2 * (size_t)NB * HW * 64);
        float4 v3 = *(const float4*)(p + 3 * (size_t)NB * HW * 64);
        bf16x4 pk = {(bf16)((v0.x + v1.x + v2.x + v3.x) * invZ),
                     (bf16)((v0.y + v1.y + v2.y + v3.y) * invZ),
                     (bf16)((v0.z + v1.z + v2.z + v3.z) * invZ),
                     (bf16)((v0.w + v1.w + v2.w + v3.w) * invZ)};
        *(bf16x4*)(sO + r * 72 + c4 * 4) = pk;
    }
    __syncthreads();

    // wave w owns co in [64w, 64w+64): 4 m-tiles of 16; single 16-pos n-tile
    const float* gp = g + ((size_t)n * CIN) * HW;
    float* op = out + ((size_t)n * CIN) * HW;
    bf16x8 b0 = *(const bf16x8*)(sO + l15 * 72 + 0 * 32 + q4 * 8);
    bf16x8 b1 = *(const bf16x8*)(sO + l15 * 72 + 1 * 32 + q4 * 8);
    #pragma unroll
    for (int mt = 0; mt < 4; ++mt) {
        const float* Wp = Watt + (w * 64 + mt * 16 + l15) * 64 + q4 * 8;
        float4 f0 = *(const float4*)(Wp);
        float4 f1 = *(const float4*)(Wp + 4);
        float4 f2 = *(const float4*)(Wp + 32);
        float4 f3 = *(const float4*)(Wp + 36);
        bf16x8 a0 = {(bf16)f0.x, (bf16)f0.y, (bf16)f0.z, (bf16)f0.w,
                     (bf16)f1.x, (bf16)f1.y, (bf16)f1.z, (bf16)f1.w};
        bf16x8 a1 = {(bf16)f2.x, (bf16)f2.y, (bf16)f2.z, (bf16)f2.w,
                     (bf16)f3.x, (bf16)f3.y, (bf16)f3.z, (bf16)f3.w};
        f32x4 acc = {};
        acc = __builtin_amdgcn_mfma_f32_16x16x32_bf16(a0, b0, acc, 0, 0, 0);
        acc = __builtin_amdgcn_mfma_f32_16x16x32_bf16(a1, b1, acc, 0, 0, 0);
        const int co = w * 64 + mt * 16 + q4 * 4;
        const int pos = jbase + l15;
        const float c0 = batt[co], c1 = batt[co + 1], c2 = batt[co + 2], c3 = batt[co + 3];
        const float g0 = gp[(co + 0) * HW + pos], g1 = gp[(co + 1) * HW + pos];
        const float g2 = gp[(co + 2) * HW + pos], g3 = gp[(co + 3) * HW + pos];
        op[(co + 0) * HW + pos] = g0 * (acc.x + c0 + 1.0f);
        op[(co + 1) * HW + pos] = g1 * (acc.y + c1 + 1.0f);
        op[(co + 2) * HW + pos] = g2 * (acc.z + c2 + 1.0f);
        op[(co + 3) * HW + pos] = g3 * (acc.w + c3 + 1.0f);
    }
}

extern "C" void kernel_launch(void* const* d_in, const int* in_sizes, int n_in,
                              void* d_out, int out_size, void* d_ws, size_t ws_size,
                              hipStream_t stream) {
    const float* x    = (const float*)d_in[0];
    const float* g    = (const float*)d_in[1];
    const float* Wq   = (const float*)d_in[2];
    const float* bq   = (const float*)d_in[3];
    const float* Wk   = (const float*)d_in[4];
    const float* bk   = (const float*)d_in[5];
    const float* Wv   = (const float*)d_in[6];
    const float* bv   = (const float*)d_in[7];
    const float* Watt = (const float*)d_in[8];
    const float* batt = (const float*)d_in[9];
    float* out = (float*)d_out;

    char* ws = (char*)d_ws;
    const size_t qkv_sz = (size_t)NB * HW * CRED * sizeof(bf16);   // 4,718,592 B
    bf16*  qT = (bf16*)(ws);
    bf16*  kT = (bf16*)(ws + qkv_sz);
    bf16*  vv = (bf16*)(ws + 2 * qkv_sz);
    float* OTp = (float*)(ws + 3 * qkv_sz);                        // 4 x 9,437,184 B
    float* Z  = (float*)(ws + 3 * qkv_sz + (size_t)NIG * NB * HW * CRED * sizeof(float));

    hipMemsetAsync(Z, 0, NB * sizeof(float), stream);

    dim3 blk(256);
    qkv_kernel<<<dim3(NJT, NB), blk, 0, stream>>>(x, Wq, bq, Wk, bk, Wv, bv, qT, kT, vv);
    attn_kernel<<<dim3(NJT, NIG, NB), blk, 0, stream>>>(qT, kT, vv, OTp, Z);
    out_kernel<<<dim3(HW / 16, NB), blk, 0, stream>>>(OTp, Z, Watt, batt, g, out);
}

// Round 3
// 275.990 us; speedup vs baseline: 1.1924x; 1.1924x over previous
//
#include <hip/hip_runtime.h>
#include <hip/hip_bf16.h>
#include <stdint.h>

#define NB   16
#define CIN  256
#define CRED 64
#define HW   2304
#define NJT  36   // 2304/64 j-tiles (attn)
#define NIG  2    // i-dimension split groups
#define NIT  18   // i-tiles per group (36/2)

typedef __bf16 bf16;
typedef __bf16 bf16x8 __attribute__((ext_vector_type(8)));
typedef __bf16 bf16x4 __attribute__((ext_vector_type(4)));
typedef float  f32x4  __attribute__((ext_vector_type(4)));

// ---------------- Kernel 1: fused QKV 1x1 convs, 32-pos j-tiles ----------------
// x [N][256][2304] f32 -> qT [N][2304][64] bf16, kT [N][2304][64] bf16, v [N][64][2304] bf16
__global__ __launch_bounds__(256) void qkv_kernel(
    const float* __restrict__ x,
    const float* __restrict__ Wq, const float* __restrict__ bq,
    const float* __restrict__ Wk, const float* __restrict__ bk,
    const float* __restrict__ Wv, const float* __restrict__ bv,
    bf16* __restrict__ qT, bf16* __restrict__ kT, bf16* __restrict__ v)
{
    __shared__ __align__(16) bf16 sX[32 * 264];  // xT[pos][cin], stride 264 (pad 8)
    const int jt = blockIdx.x, n = blockIdx.y;
    const int jbase = jt * 32;
    const int tid = threadIdx.x;
    const int lane = tid & 63, w = tid >> 6;
    const int l15 = lane & 15, q4 = lane >> 4;

    // stage xT (transpose + cvt bf16): coalesced float4 reads, scalar LDS writes
    const float* xn = x + ((size_t)n * CIN) * HW + jbase;
    #pragma unroll
    for (int it = 0; it < 8; ++it) {
        int idx = tid + 256 * it;          // 2048 float4s total
        int c = idx >> 3, p4 = idx & 7;
        const float4 vv = *(const float4*)(xn + c * HW + p4 * 4);
        sX[(p4 * 4 + 0) * 264 + c] = (bf16)vv.x;
        sX[(p4 * 4 + 1) * 264 + c] = (bf16)vv.y;
        sX[(p4 * 4 + 2) * 264 + c] = (bf16)vv.z;
        sX[(p4 * 4 + 3) * 264 + c] = (bf16)vv.w;
    }
    __syncthreads();

    const float* Ws[3] = {Wq, Wk, Wv};
    const float* bs[3] = {bq, bk, bv};
    #pragma unroll
    for (int wi = 0; wi < 3; ++wi) {
        // A-frags from global weights (L2-resident), cvt to bf16
        bf16x8 a[8];
        const float* Wp = Ws[wi] + (w * 16 + l15) * CIN + q4 * 8;
        #pragma unroll
        for (int ks = 0; ks < 8; ++ks) {
            float4 f0 = *(const float4*)(Wp + ks * 32);
            float4 f1 = *(const float4*)(Wp + ks * 32 + 4);
            bf16x8 t = {(bf16)f0.x, (bf16)f0.y, (bf16)f0.z, (bf16)f0.w,
                        (bf16)f1.x, (bf16)f1.y, (bf16)f1.z, (bf16)f1.w};
            a[ks] = t;
        }
        f32x4 acc[2] = {};
        #pragma unroll
        for (int nt = 0; nt < 2; ++nt) {
            #pragma unroll
            for (int ks = 0; ks < 8; ++ks) {
                bf16x8 b = *(const bf16x8*)(sX + (nt * 16 + l15) * 264 + ks * 32 + q4 * 8);
                acc[nt] = __builtin_amdgcn_mfma_f32_16x16x32_bf16(a[ks], b, acc[nt], 0, 0, 0);
            }
        }
        const int crb = w * 16 + q4 * 4;   // C/D row = outc
        const float b0 = bs[wi][crb], b1 = bs[wi][crb + 1],
                    b2 = bs[wi][crb + 2], b3 = bs[wi][crb + 3];
        if (wi < 2) {
            bf16* dst = (wi == 0 ? qT : kT) + ((size_t)n * HW) * 64;
            #pragma unroll
            for (int nt = 0; nt < 2; ++nt) {
                int pos = jbase + nt * 16 + l15;
                bf16x4 pk = {(bf16)(acc[nt].x + b0), (bf16)(acc[nt].y + b1),
                             (bf16)(acc[nt].z + b2), (bf16)(acc[nt].w + b3)};
                *(bf16x4*)(dst + pos * 64 + crb) = pk;
            }
        } else {
            bf16* dst = v + ((size_t)n * CRED) * HW;
            #pragma unroll
            for (int nt = 0; nt < 2; ++nt) {
                int pos = jbase + nt * 16 + l15;
                dst[(crb + 0) * HW + pos] = (bf16)(acc[nt].x + b0);
                dst[(crb + 1) * HW + pos] = (bf16)(acc[nt].y + b1);
                dst[(crb + 2) * HW + pos] = (bf16)(acc[nt].z + b2);
                dst[(crb + 3) * HW + pos] = (bf16)(acc[nt].w + b3);
            }
        }
    }
}

// ---------------- Kernel 2: fused KtQ -> exp -> V*P, i-split 2 ways ----------------
// qT/kT [N][2304][64] bf16, v [N][64][2304] bf16
// -> OTp [NIG][N][2304][64] f32 (unnormalized partials), Z[N]
// LDS 27 KB (sP aliases the dead sQ) -> 5 blocks/CU; launch_bounds(256,5) caps VGPR ~102
__global__ __launch_bounds__(256, 5) void attn_kernel(
    const bf16* __restrict__ qT, const bf16* __restrict__ kT,
    const bf16* __restrict__ v,
    float* __restrict__ OTp, float* __restrict__ Z)
{
    __shared__ __align__(16) bf16 sQP[64 * 72];  // Q during preload, then P
    __shared__ __align__(16) bf16 sK[64 * 72];
    __shared__ __align__(16) bf16 sV[64 * 72];
    const int jt = blockIdx.x, ig = blockIdx.y, n = blockIdx.z;
    const int jbase = jt * 64;
    const int tid = threadIdx.x;
    const int lane = tid & 63, w = tid >> 6;
    const int l15 = lane & 15, q4 = lane >> 4;

    // stage Q tile once: straight copy (qT rows are contiguous 64 bf16 = 8 uint4)
    {
        const uint4* src = (const uint4*)(qT + ((size_t)n * HW + jbase) * 64);
        uint4* dst = (uint4*)sQP;
        for (int i = tid; i < 512; i += 256) {
            int r = i >> 3, c = i & 7;
            dst[r * 9 + c] = src[r * 8 + c];
        }
    }
    __syncthreads();
    // Q fragments are loop-invariant: preload to registers (8 x bf16x8 = 32 VGPRs)
    bf16x8 qf[4][2];
    #pragma unroll
    for (int nt = 0; nt < 4; ++nt)
        #pragma unroll
        for (int ks = 0; ks < 2; ++ks)
            qf[nt][ks] = *(const bf16x8*)(sQP + (nt * 16 + l15) * 72 + ks * 32 + q4 * 8);

    f32x4 oacc[4] = {};
    float zacc = 0.f;
    const uint4* ksrc = (const uint4*)(kT + ((size_t)n * HW) * 64);
    const bf16* vbase = v + ((size_t)n * CRED) * HW;

    for (int it = 0; it < NIT; ++it) {
        const int ibase = (ig * NIT + it) * 64;
        __syncthreads();   // prior iter's reads of sK/sV/sQP(P) done (also covers Q preload)
        {   // stage K tile (straight copy) and V tile (row segments)
            uint4* dk = (uint4*)sK;
            uint4* dv = (uint4*)sV;
            const uint4* sk = ksrc + ibase * 8;
            for (int i = tid; i < 512; i += 256) {
                int r = i >> 3, c = i & 7;
                dk[r * 9 + c] = sk[r * 8 + c];
                dv[r * 9 + c] = *(const uint4*)(vbase + r * HW + ibase + c * 8);
            }
        }
        __syncthreads();
        // S = K_i^T Q_j : wave w owns i-rows [16w,16w+16), all 64 j
        bf16x8 kf0 = *(const bf16x8*)(sK + (w * 16 + l15) * 72 + 0 * 32 + q4 * 8);
        bf16x8 kf1 = *(const bf16x8*)(sK + (w * 16 + l15) * 72 + 1 * 32 + q4 * 8);
        #pragma unroll
        for (int nt = 0; nt < 4; ++nt) {
            f32x4 accs = {};
            accs = __builtin_amdgcn_mfma_f32_16x16x32_bf16(kf0, qf[nt][0], accs, 0, 0, 0);
            accs = __builtin_amdgcn_mfma_f32_16x16x32_bf16(kf1, qf[nt][1], accs, 0, 0, 0);
            // exp in fp32 (no max-shift: logits bounded, exp < 1.3e9 fits fp32)
            float p0 = __expf(accs.x), p1 = __expf(accs.y);
            float p2 = __expf(accs.z), p3 = __expf(accs.w);
            zacc += (p0 + p1) + (p2 + p3);
            // P transposed into B-operand layout sQP[j][i]
            bf16x4 pk = {(bf16)p0, (bf16)p1, (bf16)p2, (bf16)p3};
            *(bf16x4*)(sQP + (nt * 16 + l15) * 72 + w * 16 + q4 * 4) = pk;
        }
        __syncthreads();
        // O += V_i * P : wave w owns c-rows [16w,16w+16)
        bf16x8 vf0 = *(const bf16x8*)(sV + (w * 16 + l15) * 72 + 0 * 32 + q4 * 8);
        bf16x8 vf1 = *(const bf16x8*)(sV + (w * 16 + l15) * 72 + 1 * 32 + q4 * 8);
        #pragma unroll
        for (int nt = 0; nt < 4; ++nt) {
            bf16x8 p0 = *(const bf16x8*)(sQP + (nt * 16 + l15) * 72 + 0 * 32 + q4 * 8);
            bf16x8 p1 = *(const bf16x8*)(sQP + (nt * 16 + l15) * 72 + 1 * 32 + q4 * 8);
            oacc[nt] = __builtin_amdgcn_mfma_f32_16x16x32_bf16(vf0, p0, oacc[nt], 0, 0, 0);
            oacc[nt] = __builtin_amdgcn_mfma_f32_16x16x32_bf16(vf1, p1, oacc[nt], 0, 0, 0);
        }
    }
    // write unnormalized partial O transposed: OTp[ig][n][pos][cr]
    float* OTn = OTp + (((size_t)ig * NB + n) * HW) * 64;
    #pragma unroll
    for (int nt = 0; nt < 4; ++nt) {
        int pos = jbase + nt * 16 + l15;
        *(f32x4*)(OTn + pos * 64 + w * 16 + q4 * 4) = oacc[nt];
    }
    // per-batch Z: wave reduce then one atomic per wave
    #pragma unroll
    for (int off = 32; off > 0; off >>= 1) zacc += __shfl_down(zacc, off);
    if (lane == 0) atomicAdd(Z + n, zacc);
}

// ---------------- Kernel 3: out = g * (Watt @ (sum_partials(O)/Z) + batt) + g ----------
// 16-pos j-tiles for parallelism: grid (144, 16)
__global__ __launch_bounds__(256) void out_kernel(
    const float* __restrict__ OTp, const float* __restrict__ Z,
    const float* __restrict__ Watt, const float* __restrict__ batt,
    const float* __restrict__ g, float* __restrict__ out)
{
    __shared__ __align__(16) bf16 sO[16 * 72];  // normalized O, [pos][cr]
    const int jt = blockIdx.x, n = blockIdx.y;
    const int jbase = jt * 16;
    const int tid = threadIdx.x;
    const int lane = tid & 63, w = tid >> 6;
    const int l15 = lane & 15, q4 = lane >> 4;
    const float invZ = 1.0f / Z[n];

    // sum NIG partials, normalize, cvt bf16: 256 threads x 1 float4 each
    {
        int r = tid >> 4, c4 = tid & 15;
        const float* p = OTp + (((size_t)n * HW) + jbase + r) * 64 + c4 * 4;
        float4 v0 = *(const float4*)(p);
        float4 v1 = *(const float4*)(p + (size_t)NB * HW * 64);
        bf16x4 pk = {(bf16)((v0.x + v1.x) * invZ),
                     (bf16)((v0.y + v1.y) * invZ),
                     (bf16)((v0.z + v1.z) * invZ),
                     (bf16)((v0.w + v1.w) * invZ)};
        *(bf16x4*)(sO + r * 72 + c4 * 4) = pk;
    }
    __syncthreads();

    // wave w owns co in [64w, 64w+64): 4 m-tiles of 16; single 16-pos n-tile
    const float* gp = g + ((size_t)n * CIN) * HW;
    float* op = out + ((size_t)n * CIN) * HW;
    bf16x8 b0 = *(const bf16x8*)(sO + l15 * 72 + 0 * 32 + q4 * 8);
    bf16x8 b1 = *(const bf16x8*)(sO + l15 * 72 + 1 * 32 + q4 * 8);
    #pragma unroll
    for (int mt = 0; mt < 4; ++mt) {
        const float* Wp = Watt + (w * 64 + mt * 16 + l15) * 64 + q4 * 8;
        float4 f0 = *(const float4*)(Wp);
        float4 f1 = *(const float4*)(Wp + 4);
        float4 f2 = *(const float4*)(Wp + 32);
        float4 f3 = *(const float4*)(Wp + 36);
        bf16x8 a0 = {(bf16)f0.x, (bf16)f0.y, (bf16)f0.z, (bf16)f0.w,
                     (bf16)f1.x, (bf16)f1.y, (bf16)f1.z, (bf16)f1.w};
        bf16x8 a1 = {(bf16)f2.x, (bf16)f2.y, (bf16)f2.z, (bf16)f2.w,
                     (bf16)f3.x, (bf16)f3.y, (bf16)f3.z, (bf16)f3.w};
        f32x4 acc = {};
        acc = __builtin_amdgcn_mfma_f32_16x16x32_bf16(a0, b0, acc, 0, 0, 0);
        acc = __builtin_amdgcn_mfma_f32_16x16x32_bf16(a1, b1, acc, 0, 0, 0);
        const int co = w * 64 + mt * 16 + q4 * 4;
        const int pos = jbase + l15;
        const float c0 = batt[co], c1 = batt[co + 1], c2 = batt[co + 2], c3 = batt[co + 3];
        const float g0 = gp[(co + 0) * HW + pos], g1 = gp[(co + 1) * HW + pos];
        const float g2 = gp[(co + 2) * HW + pos], g3 = gp[(co + 3) * HW + pos];
        op[(co + 0) * HW + pos] = g0 * (acc.x + c0 + 1.0f);
        op[(co + 1) * HW + pos] = g1 * (acc.y + c1 + 1.0f);
        op[(co + 2) * HW + pos] = g2 * (acc.z + c2 + 1.0f);
        op[(co + 3) * HW + pos] = g3 * (acc.w + c3 + 1.0f);
    }
}

extern "C" void kernel_launch(void* const* d_in, const int* in_sizes, int n_in,
                              void* d_out, int out_size, void* d_ws, size_t ws_size,
                              hipStream_t stream) {
    const float* x    = (const float*)d_in[0];
    const float* g    = (const float*)d_in[1];
    const float* Wq   = (const float*)d_in[2];
    const float* bq   = (const float*)d_in[3];
    const float* Wk   = (const float*)d_in[4];
    const float* bk   = (const float*)d_in[5];
    const float* Wv   = (const float*)d_in[6];
    const float* bv   = (const float*)d_in[7];
    const float* Watt = (const float*)d_in[8];
    const float* batt = (const float*)d_in[9];
    float* out = (float*)d_out;

    char* ws = (char*)d_ws;
    const size_t qkv_sz = (size_t)NB * HW * CRED * sizeof(bf16);   // 4,718,592 B
    bf16*  qT = (bf16*)(ws);
    bf16*  kT = (bf16*)(ws + qkv_sz);
    bf16*  vv = (bf16*)(ws + 2 * qkv_sz);
    float* OTp = (float*)(ws + 3 * qkv_sz);                        // NIG x 9,437,184 B
    float* Z  = (float*)(ws + 3 * qkv_sz + (size_t)NIG * NB * HW * CRED * sizeof(float));

    hipMemsetAsync(Z, 0, NB * sizeof(float), stream);

    dim3 blk(256);
    qkv_kernel<<<dim3(HW / 32, NB), blk, 0, stream>>>(x, Wq, bq, Wk, bk, Wv, bv, qT, kT, vv);
    attn_kernel<<<dim3(NJT, NIG, NB), blk, 0, stream>>>(qT, kT, vv, OTp, Z);
    out_kernel<<<dim3(HW / 16, NB), blk, 0, stream>>>(OTp, Z, Watt, batt, g, out);
}

// Round 4
// 251.417 us; speedup vs baseline: 1.3090x; 1.0977x over previous
//
#include <hip/hip_runtime.h>
#include <hip/hip_bf16.h>
#include <stdint.h>

#define NB   16
#define CIN  256
#define CRED 64
#define HW   2304
#define NJT  36   // 2304/64 j-tiles (attn)
#define NIG  2    // i-dimension split groups
#define NIT  18   // i-tiles per group (36/2)

typedef __bf16 bf16;
typedef __bf16 bf16x8 __attribute__((ext_vector_type(8)));
typedef __bf16 bf16x4 __attribute__((ext_vector_type(4)));
typedef float  f32x4  __attribute__((ext_vector_type(4)));

// ---------------- Kernel 0: weight prep (fp32 -> bf16; Wq,bq scaled by 1/ln2) ------
// so attention can use exp2 (native v_exp_f32) instead of exp.
__global__ __launch_bounds__(256) void prep_kernel(
    const float* __restrict__ Wq, const float* __restrict__ bq,
    const float* __restrict__ Wk, const float* __restrict__ Wv,
    const float* __restrict__ Watt,
    bf16* __restrict__ Wqb, bf16* __restrict__ Wkb, bf16* __restrict__ Wvb,
    bf16* __restrict__ Wab, float* __restrict__ bqs)
{
    const float INVLN2 = 1.44269504088896f;
    int i = blockIdx.x * 256 + threadIdx.x;   // 64 blocks -> 16384 threads
    Wqb[i] = (bf16)(Wq[i] * INVLN2);
    Wkb[i] = (bf16)Wk[i];
    Wvb[i] = (bf16)Wv[i];
    Wab[i] = (bf16)Watt[i];
    if (i < CRED) bqs[i] = bq[i] * INVLN2;
}

// ---------------- Kernel 1: fused QKV 1x1 convs, 32-pos j-tiles, bf16 weights ------
// x [N][256][2304] f32 -> qT [N][2304][64] bf16 (q/ln2), kT [N][2304][64], v [N][64][2304]
__global__ __launch_bounds__(256) void qkv_kernel(
    const float* __restrict__ x,
    const bf16* __restrict__ Wqb, const float* __restrict__ bqs,
    const bf16* __restrict__ Wkb, const float* __restrict__ bk,
    const bf16* __restrict__ Wvb, const float* __restrict__ bv,
    bf16* __restrict__ qT, bf16* __restrict__ kT, bf16* __restrict__ v)
{
    __shared__ __align__(16) bf16 sX[32 * 264];  // xT[pos][cin], stride 264 (pad 8)
    const int jt = blockIdx.x, n = blockIdx.y;
    const int jbase = jt * 32;
    const int tid = threadIdx.x;
    const int lane = tid & 63, w = tid >> 6;
    const int l15 = lane & 15, q4 = lane >> 4;

    // stage xT (transpose + cvt bf16): coalesced float4 reads, scalar LDS writes
    const float* xn = x + ((size_t)n * CIN) * HW + jbase;
    #pragma unroll
    for (int it = 0; it < 8; ++it) {
        int idx = tid + 256 * it;          // 2048 float4s total
        int c = idx >> 3, p4 = idx & 7;
        const float4 vv = *(const float4*)(xn + c * HW + p4 * 4);
        sX[(p4 * 4 + 0) * 264 + c] = (bf16)vv.x;
        sX[(p4 * 4 + 1) * 264 + c] = (bf16)vv.y;
        sX[(p4 * 4 + 2) * 264 + c] = (bf16)vv.z;
        sX[(p4 * 4 + 3) * 264 + c] = (bf16)vv.w;
    }
    __syncthreads();

    const bf16*  Ws[3] = {Wqb, Wkb, Wvb};
    const float* bs[3] = {bqs, bk, bv};
    #pragma unroll
    for (int wi = 0; wi < 3; ++wi) {
        // A-frags: direct b128 loads of pre-converted bf16 weights (L2-resident)
        bf16x8 a[8];
        const bf16* Wp = Ws[wi] + (w * 16 + l15) * CIN + q4 * 8;
        #pragma unroll
        for (int ks = 0; ks < 8; ++ks) a[ks] = *(const bf16x8*)(Wp + ks * 32);
        f32x4 acc[2] = {};
        #pragma unroll
        for (int nt = 0; nt < 2; ++nt) {
            #pragma unroll
            for (int ks = 0; ks < 8; ++ks) {
                bf16x8 b = *(const bf16x8*)(sX + (nt * 16 + l15) * 264 + ks * 32 + q4 * 8);
                acc[nt] = __builtin_amdgcn_mfma_f32_16x16x32_bf16(a[ks], b, acc[nt], 0, 0, 0);
            }
        }
        const int crb = w * 16 + q4 * 4;   // C/D row = outc
        const float b0 = bs[wi][crb], b1 = bs[wi][crb + 1],
                    b2 = bs[wi][crb + 2], b3 = bs[wi][crb + 3];
        if (wi < 2) {
            bf16* dst = (wi == 0 ? qT : kT) + ((size_t)n * HW) * 64;
            #pragma unroll
            for (int nt = 0; nt < 2; ++nt) {
                int pos = jbase + nt * 16 + l15;
                bf16x4 pk = {(bf16)(acc[nt].x + b0), (bf16)(acc[nt].y + b1),
                             (bf16)(acc[nt].z + b2), (bf16)(acc[nt].w + b3)};
                *(bf16x4*)(dst + pos * 64 + crb) = pk;
            }
        } else {
            bf16* dst = v + ((size_t)n * CRED) * HW;
            #pragma unroll
            for (int nt = 0; nt < 2; ++nt) {
                int pos = jbase + nt * 16 + l15;
                dst[(crb + 0) * HW + pos] = (bf16)(acc[nt].x + b0);
                dst[(crb + 1) * HW + pos] = (bf16)(acc[nt].y + b1);
                dst[(crb + 2) * HW + pos] = (bf16)(acc[nt].z + b2);
                dst[(crb + 3) * HW + pos] = (bf16)(acc[nt].w + b3);
            }
        }
    }
}

// ---------------- Kernel 2: fused KtQ -> exp -> V*P, reg-prefetch pipeline ----------
// qT holds q/ln2, so P = exp2(S'). i-split 2 ways; sP aliases dead sQ (27 KB LDS).
__global__ __launch_bounds__(256, 4) void attn_kernel(
    const bf16* __restrict__ qT, const bf16* __restrict__ kT,
    const bf16* __restrict__ v,
    float* __restrict__ OTp, float* __restrict__ Z)
{
    __shared__ __align__(16) bf16 sQP[64 * 72];  // Q during preload, then P
    __shared__ __align__(16) bf16 sK[64 * 72];
    __shared__ __align__(16) bf16 sV[64 * 72];
    const int jt = blockIdx.x, ig = blockIdx.y, n = blockIdx.z;
    const int jbase = jt * 64;
    const int tid = threadIdx.x;
    const int lane = tid & 63, w = tid >> 6;
    const int l15 = lane & 15, q4 = lane >> 4;

    // stage Q tile once (contiguous rows of 64 bf16 = 8 uint4)
    {
        const uint4* src = (const uint4*)(qT + ((size_t)n * HW + jbase) * 64);
        uint4* dst = (uint4*)sQP;
        for (int i = tid; i < 512; i += 256) {
            int r = i >> 3, c = i & 7;
            dst[r * 9 + c] = src[r * 8 + c];
        }
    }
    __syncthreads();
    // Q fragments are loop-invariant: preload to registers
    bf16x8 qf[4][2];
    #pragma unroll
    for (int nt = 0; nt < 4; ++nt)
        #pragma unroll
        for (int ks = 0; ks < 2; ++ks)
            qf[nt][ks] = *(const bf16x8*)(sQP + (nt * 16 + l15) * 72 + ks * 32 + q4 * 8);

    f32x4 oacc[4] = {};
    float zacc = 0.f;
    const uint4* ksrc = (const uint4*)(kT + ((size_t)n * HW) * 64);
    const bf16* vbase = v + ((size_t)n * CRED) * HW;

    // per-thread staging coords: rows r0 and r0+32, uint4-col c0
    const int r0 = tid >> 3, c0 = tid & 7;
    const int ibase0 = ig * NIT * 64;

    // prologue: prefetch tile 0 into registers
    uint4 kr0 = ksrc[(ibase0 + r0) * 8 + c0];
    uint4 kr1 = ksrc[(ibase0 + r0 + 32) * 8 + c0];
    uint4 vr0 = *(const uint4*)(vbase + (size_t)r0 * HW + ibase0 + c0 * 8);
    uint4 vr1 = *(const uint4*)(vbase + (size_t)(r0 + 32) * HW + ibase0 + c0 * 8);

    uint4* dk = (uint4*)sK;
    uint4* dv = (uint4*)sV;

    for (int it = 0; it < NIT; ++it) {
        const int ibase = ibase0 + it * 64;
        __syncthreads();   // prior iter's compute done with sK/sV/sQP
        // commit prefetched tile to LDS (vmcnt wait lands here, with a full
        // compute phase of slack behind it)
        dk[r0 * 9 + c0] = kr0;
        dk[(r0 + 32) * 9 + c0] = kr1;
        dv[r0 * 9 + c0] = vr0;
        dv[(r0 + 32) * 9 + c0] = vr1;
        // issue next tile's loads (wrap to self on last iter; values unused)
        const int nbase = (it + 1 < NIT) ? ibase + 64 : ibase;
        kr0 = ksrc[(nbase + r0) * 8 + c0];
        kr1 = ksrc[(nbase + r0 + 32) * 8 + c0];
        vr0 = *(const uint4*)(vbase + (size_t)r0 * HW + nbase + c0 * 8);
        vr1 = *(const uint4*)(vbase + (size_t)(r0 + 32) * HW + nbase + c0 * 8);
        __syncthreads();   // sK/sV visible

        // S' = (K_i^T Q_j)/ln2 : wave w owns i-rows [16w,16w+16), all 64 j
        bf16x8 kf0 = *(const bf16x8*)(sK + (w * 16 + l15) * 72 + 0 * 32 + q4 * 8);
        bf16x8 kf1 = *(const bf16x8*)(sK + (w * 16 + l15) * 72 + 1 * 32 + q4 * 8);
        #pragma unroll
        for (int nt = 0; nt < 4; ++nt) {
            f32x4 accs = {};
            accs = __builtin_amdgcn_mfma_f32_16x16x32_bf16(kf0, qf[nt][0], accs, 0, 0, 0);
            accs = __builtin_amdgcn_mfma_f32_16x16x32_bf16(kf1, qf[nt][1], accs, 0, 0, 0);
            // exp2 (native v_exp_f32); logits bounded so exp < ~2^31 fits fp32
            float p0 = exp2f(accs.x), p1 = exp2f(accs.y);
            float p2 = exp2f(accs.z), p3 = exp2f(accs.w);
            zacc += (p0 + p1) + (p2 + p3);
            // P transposed into B-operand layout sQP[j][i]
            bf16x4 pk = {(bf16)p0, (bf16)p1, (bf16)p2, (bf16)p3};
            *(bf16x4*)(sQP + (nt * 16 + l15) * 72 + w * 16 + q4 * 4) = pk;
        }
        __syncthreads();   // P visible
        // O += V_i * P : wave w owns c-rows [16w,16w+16)
        bf16x8 vf0 = *(const bf16x8*)(sV + (w * 16 + l15) * 72 + 0 * 32 + q4 * 8);
        bf16x8 vf1 = *(const bf16x8*)(sV + (w * 16 + l15) * 72 + 1 * 32 + q4 * 8);
        #pragma unroll
        for (int nt = 0; nt < 4; ++nt) {
            bf16x8 p0 = *(const bf16x8*)(sQP + (nt * 16 + l15) * 72 + 0 * 32 + q4 * 8);
            bf16x8 p1 = *(const bf16x8*)(sQP + (nt * 16 + l15) * 72 + 1 * 32 + q4 * 8);
            oacc[nt] = __builtin_amdgcn_mfma_f32_16x16x32_bf16(vf0, p0, oacc[nt], 0, 0, 0);
            oacc[nt] = __builtin_amdgcn_mfma_f32_16x16x32_bf16(vf1, p1, oacc[nt], 0, 0, 0);
        }
    }
    // write unnormalized partial O transposed: OTp[ig][n][pos][cr]
    float* OTn = OTp + (((size_t)ig * NB + n) * HW) * 64;
    #pragma unroll
    for (int nt = 0; nt < 4; ++nt) {
        int pos = jbase + nt * 16 + l15;
        *(f32x4*)(OTn + pos * 64 + w * 16 + q4 * 4) = oacc[nt];
    }
    // per-batch Z: wave reduce then one atomic per wave
    #pragma unroll
    for (int off = 32; off > 0; off >>= 1) zacc += __shfl_down(zacc, off);
    if (lane == 0) atomicAdd(Z + n, zacc);
}

// ---------------- Kernel 3: out = g * (Watt @ (sum(O)/Z) + batt) + g ----------------
// 64-pos j-tiles: grid (36, 16); 32 MFMA/wave, bf16 weights
__global__ __launch_bounds__(256) void out_kernel(
    const float* __restrict__ OTp, const float* __restrict__ Z,
    const bf16* __restrict__ Wab, const float* __restrict__ batt,
    const float* __restrict__ g, float* __restrict__ out)
{
    __shared__ __align__(16) bf16 sO[64 * 72];  // normalized O, [pos][cr]
    const int jt = blockIdx.x, n = blockIdx.y;
    const int jbase = jt * 64;
    const int tid = threadIdx.x;
    const int lane = tid & 63, w = tid >> 6;
    const int l15 = lane & 15, q4 = lane >> 4;
    const float invZ = 1.0f / Z[n];

    // sum NIG partials, normalize, cvt bf16: 1024 float4s over 256 threads
    for (int i = tid; i < 1024; i += 256) {
        int r = i >> 4, c4 = i & 15;
        const float* p = OTp + (((size_t)n * HW) + jbase + r) * 64 + c4 * 4;
        float4 v0 = *(const float4*)(p);
        float4 v1 = *(const float4*)(p + (size_t)NB * HW * 64);
        bf16x4 pk = {(bf16)((v0.x + v1.x) * invZ),
                     (bf16)((v0.y + v1.y) * invZ),
                     (bf16)((v0.z + v1.z) * invZ),
                     (bf16)((v0.w + v1.w) * invZ)};
        *(bf16x4*)(sO + r * 72 + c4 * 4) = pk;
    }
    __syncthreads();

    // B-frags for all 4 pos-tiles
    bf16x8 bfr[4][2];
    #pragma unroll
    for (int nt = 0; nt < 4; ++nt)
        #pragma unroll
        for (int ks = 0; ks < 2; ++ks)
            bfr[nt][ks] = *(const bf16x8*)(sO + (nt * 16 + l15) * 72 + ks * 32 + q4 * 8);

    const float* gp = g + ((size_t)n * CIN) * HW;
    float* op = out + ((size_t)n * CIN) * HW;
    #pragma unroll
    for (int mt = 0; mt < 4; ++mt) {
        const bf16* Wp = Wab + (w * 64 + mt * 16 + l15) * 64 + q4 * 8;
        bf16x8 a0 = *(const bf16x8*)(Wp);
        bf16x8 a1 = *(const bf16x8*)(Wp + 32);
        const int co = w * 64 + mt * 16 + q4 * 4;
        const float c0 = batt[co], c1 = batt[co + 1], c2 = batt[co + 2], c3 = batt[co + 3];
        #pragma unroll
        for (int nt = 0; nt < 4; ++nt) {
            f32x4 acc = {};
            acc = __builtin_amdgcn_mfma_f32_16x16x32_bf16(a0, bfr[nt][0], acc, 0, 0, 0);
            acc = __builtin_amdgcn_mfma_f32_16x16x32_bf16(a1, bfr[nt][1], acc, 0, 0, 0);
            const int pos = jbase + nt * 16 + l15;
            const float g0 = gp[(co + 0) * HW + pos], g1 = gp[(co + 1) * HW + pos];
            const float g2 = gp[(co + 2) * HW + pos], g3 = gp[(co + 3) * HW + pos];
            op[(co + 0) * HW + pos] = g0 * (acc.x + c0 + 1.0f);
            op[(co + 1) * HW + pos] = g1 * (acc.y + c1 + 1.0f);
            op[(co + 2) * HW + pos] = g2 * (acc.z + c2 + 1.0f);
            op[(co + 3) * HW + pos] = g3 * (acc.w + c3 + 1.0f);
        }
    }
}

extern "C" void kernel_launch(void* const* d_in, const int* in_sizes, int n_in,
                              void* d_out, int out_size, void* d_ws, size_t ws_size,
                              hipStream_t stream) {
    const float* x    = (const float*)d_in[0];
    const float* g    = (const float*)d_in[1];
    const float* Wq   = (const float*)d_in[2];
    const float* bq   = (const float*)d_in[3];
    const float* Wk   = (const float*)d_in[4];
    const float* bk   = (const float*)d_in[5];
    const float* Wv   = (const float*)d_in[6];
    const float* bv   = (const float*)d_in[7];
    const float* Watt = (const float*)d_in[8];
    const float* batt = (const float*)d_in[9];
    float* out = (float*)d_out;

    char* ws = (char*)d_ws;
    const size_t qkv_sz = (size_t)NB * HW * CRED * sizeof(bf16);   // 4,718,592 B
    bf16*  qT  = (bf16*)(ws);
    bf16*  kT  = (bf16*)(ws + qkv_sz);
    bf16*  vv  = (bf16*)(ws + 2 * qkv_sz);
    float* OTp = (float*)(ws + 3 * qkv_sz);                        // NIG x 9,437,184 B
    char*  w2  = ws + 3 * qkv_sz + (size_t)NIG * NB * HW * CRED * sizeof(float);
    float* Zp  = (float*)(w2);
    bf16*  Wqb = (bf16*)(w2 + 256);
    bf16*  Wkb = Wqb + CRED * CIN;
    bf16*  Wvb = Wkb + CRED * CIN;
    bf16*  Wab = Wvb + CRED * CIN;
    float* bqs = (float*)(Wab + CIN * CRED);

    hipMemsetAsync(Zp, 0, NB * sizeof(float), stream);

    dim3 blk(256);
    prep_kernel<<<dim3(64), blk, 0, stream>>>(Wq, bq, Wk, Wv, Watt, Wqb, Wkb, Wvb, Wab, bqs);
    qkv_kernel<<<dim3(HW / 32, NB), blk, 0, stream>>>(x, Wqb, bqs, Wkb, bk, Wvb, bv, qT, kT, vv);
    attn_kernel<<<dim3(NJT, NIG, NB), blk, 0, stream>>>(qT, kT, vv, OTp, Zp);
    out_kernel<<<dim3(NJT, NB), blk, 0, stream>>>(OTp, Zp, Wab, batt, g, out);
}